// Round 5
// baseline (201.929 us; speedup 1.0000x reference)
//
#include <hip/hip_runtime.h>
#include <hip/hip_bf16.h>

typedef unsigned short u16;
typedef unsigned int u32;
typedef __attribute__((ext_vector_type(8))) short bf16x8;
typedef __attribute__((ext_vector_type(4))) float f32x4;

#define NB 4096
#define ND 512
#define NREPS (3*NB)
#define BM 128
#define BN 128
#define BK 64
#define NKT (ND/BK)      // 8 K-tiles
#define TSZ (BM*BK)      // 8192 elems per tile buffer

// global -> LDS direct DMA, 16B/lane; LDS dest wave-uniform base + lane*16.
#define GLD16(gp, lp)                                                         \
  __builtin_amdgcn_global_load_lds(                                           \
      (const __attribute__((address_space(1))) void*)(gp),                    \
      (__attribute__((address_space(3))) void*)(lp), 16, 0, 0)

__device__ __forceinline__ u16 f2bf(float f) {
  union { float f; u32 u; } v; v.f = f;
  u32 u = v.u;
  u32 r = (u + 0x7FFFu + ((u >> 16) & 1u)) >> 16;  // round-to-nearest-even
  return (u16)r;
}

// Fused prep: waves 0..2 convert ts/i1/i2 row r -> bf16 reps + fp32 norms;
// i1/i2 rows pass through LDS to wave 3 (dist12 + minsq init).
__global__ __launch_bounds__(256) void prep_all(
    const float* __restrict__ ts, const float* __restrict__ i1,
    const float* __restrict__ i2, u16* __restrict__ reps,
    float* __restrict__ norms, float* __restrict__ dist12,
    u32* __restrict__ minsq)
{
  __shared__ float s1[ND], s2[ND];
  const int r = blockIdx.x;
  const int tid = threadIdx.x;
  const int wave = tid >> 6, lane = tid & 63;

  if (wave < 3) {
    const float* src = (wave == 0) ? ts + (size_t)r * ND
                     : (wave == 1) ? i1 + (size_t)r * ND
                     :               i2 + (size_t)r * ND;
    const float4* s4 = (const float4*)src;
    float4 a = s4[lane*2+0];
    float4 b = s4[lane*2+1];
    if (wave == 1) { ((float4*)s1)[lane*2+0] = a; ((float4*)s1)[lane*2+1] = b; }
    if (wave == 2) { ((float4*)s2)[lane*2+0] = a; ((float4*)s2)[lane*2+1] = b; }
    float ss = a.x*a.x + a.y*a.y + a.z*a.z + a.w*a.w
             + b.x*b.x + b.y*b.y + b.z*b.z + b.w*b.w;
    uint4 pk;
    pk.x = (u32)f2bf(a.x) | ((u32)f2bf(a.y) << 16);
    pk.y = (u32)f2bf(a.z) | ((u32)f2bf(a.w) << 16);
    pk.z = (u32)f2bf(b.x) | ((u32)f2bf(b.y) << 16);
    pk.w = (u32)f2bf(b.z) | ((u32)f2bf(b.w) << 16);
    *(uint4*)(reps + (size_t)(wave*NB + r) * ND + lane*8) = pk;
    #pragma unroll
    for (int off = 32; off; off >>= 1) ss += __shfl_down(ss, off);
    if (lane == 0) norms[wave*NB + r] = ss;
  }
  __syncthreads();
  if (wave == 3) {
    float ss = 0.f;
    #pragma unroll
    for (int i = 0; i < 2; ++i) {
      float4 a = ((float4*)s1)[lane*2+i];
      float4 b = ((float4*)s2)[lane*2+i];
      float d0 = a.x - b.x + 1e-6f, d1 = a.y - b.y + 1e-6f;
      float d2 = a.z - b.z + 1e-6f, d3 = a.w - b.w + 1e-6f;
      ss += d0*d0 + d1*d1 + d2*d2 + d3*d3;
    }
    #pragma unroll
    for (int off = 32; off; off >>= 1) ss += __shfl_down(ss, off);
    if (lane == 0) { dist12[r] = sqrtf(ss); minsq[r] = 0x7F800000u; }
  }
}

// Fused distance-GEMM + per-row min + diagonal picks.
// 128x128 tile, BK=64, 4 waves (2x2), 2-phase double-buffered LDS (64 KiB):
//   prologue: STAGE(buf0, k=0); sync
//   step t:   STAGE(buf[t^1], k(t+1))  [issue-early]
//             ds_read frags(buf[t]) ; 32 MFMA
//             __syncthreads()          [vmcnt(0)+lgkmcnt(0)+barrier, once/step]
//   last step peeled: compute only.
// LDS linear; XOR swizzle applied on per-lane GLOBAL source granule (m173).
__global__ __launch_bounds__(256) void gemm_min(
    const u16* __restrict__ reps, const float* __restrict__ norms,
    u32* __restrict__ minsq, float* __restrict__ lpos1,
    float* __restrict__ lpos2)
{
  __shared__ u16 As[2*TSZ];
  __shared__ u16 Bs[2*TSZ];
  const int tid  = threadIdx.x;
  const int lane = tid & 63;
  const int wave = tid >> 6;
  const int wr = wave >> 1, wc = wave & 1;
  const int fr = lane & 15, fg = lane >> 4;

  // Bijective XCD swizzle (3072 % 8 == 0), ny-fastest: each XCD works 4
  // consecutive M-panels (1 MB of A stays L2-resident) while B streams.
  const int bid = blockIdx.x;
  const int wid = (bid & 7) * 384 + (bid >> 3);
  const int mx = wid / 96, ny = wid % 96;
  const int rowBase = mx * BM;   // ts rows
  const int colBase = ny * BN;   // reps rows

  // Staging geometry: thread's 4 A-chunks + 4 B-chunks, 8 rows per chunk
  // (64 lanes x 16B = 1 KiB per GLD). Source granule is XOR-swizzled.
  const int rloc = lane >> 3;          // row within 8-row chunk
  const int sp   = lane & 7;           // physical 16B slot within row
  const u16* srcA[4]; const u16* srcB[4];
  u16* dstA[4]; u16* dstB[4];
  #pragma unroll
  for (int i = 0; i < 4; ++i) {
    const int r = wave*32 + i*8 + rloc;          // tile-local row 0..127
    const int g = sp ^ (r & 7);                  // swizzled source granule
    srcA[i] = reps + (size_t)(rowBase + r) * ND + g*8;
    srcB[i] = reps + (size_t)(colBase + r) * ND + g*8;
    dstA[i] = &As[(wave*32 + i*8) * BK];         // wave-uniform LDS base
    dstB[i] = &Bs[(wave*32 + i*8) * BK];
  }

#define STAGE(buf, koff)                                                      \
  { _Pragma("unroll")                                                         \
    for (int i = 0; i < 4; ++i) {                                             \
      GLD16(srcA[i] + (koff), dstA[i] + (buf)*TSZ);                           \
      GLD16(srcB[i] + (koff), dstB[i] + (buf)*TSZ);                           \
    } }

  f32x4 acc[4][4];
  const f32x4 zero = {0.f, 0.f, 0.f, 0.f};
  #pragma unroll
  for (int i = 0; i < 4; ++i)
    #pragma unroll
    for (int j = 0; j < 4; ++j)
      acc[i][j] = zero;

#define COMPUTE(cur)                                                          \
  { const u16* Sa = As + (cur)*TSZ;                                           \
    const u16* Sb = Bs + (cur)*TSZ;                                           \
    bf16x8 af[4][2], bfr[4][2];                                               \
    _Pragma("unroll")                                                         \
    for (int mf = 0; mf < 4; ++mf)                                            \
      _Pragma("unroll")                                                       \
      for (int ks = 0; ks < 2; ++ks) {                                        \
        const int rowA = wr*64 + mf*16 + fr;                                  \
        const int slot = ks*4 + fg;                                           \
        af[mf][ks]  = *(const bf16x8*)&Sa[rowA*BK + (slot ^ (rowA & 7))*8];   \
        const int rowB = wc*64 + mf*16 + fr;                                  \
        bfr[mf][ks] = *(const bf16x8*)&Sb[rowB*BK + (slot ^ (rowB & 7))*8];   \
      }                                                                       \
    _Pragma("unroll")                                                         \
    for (int ks = 0; ks < 2; ++ks)                                            \
      _Pragma("unroll")                                                       \
      for (int mf = 0; mf < 4; ++mf)                                          \
        _Pragma("unroll")                                                     \
        for (int nf = 0; nf < 4; ++nf)                                        \
          acc[mf][nf] = __builtin_amdgcn_mfma_f32_16x16x32_bf16(              \
              af[mf][ks], bfr[nf][ks], acc[mf][nf], 0, 0, 0);                 \
  }

  // Prologue: tile 0 into buffer 0, full drain once.
  STAGE(0, 0);
  __syncthreads();
  // Steady state: issue next tile's loads, then compute current.
  #pragma unroll
  for (int t = 0; t < NKT-1; ++t) {
    STAGE((t & 1) ^ 1, (t+1)*BK);
    COMPUTE(t & 1);
    __syncthreads();   // vmcnt(0): next tile landed; all reads of cur done
  }
  COMPUTE((NKT-1) & 1);  // peeled: no stage, no trailing barrier needed

  // Epilogue: sq = nt + nc - 2*dot; diagonal picks; row-min with exclusions.
  // C layout: col = fr, row = fg*4 + q within each 16x16 fragment.
  float ncol[4];
  #pragma unroll
  for (int nf = 0; nf < 4; ++nf)
    ncol[nf] = norms[colBase + wc*64 + nf*16 + fr];
  const float INF = __builtin_inff();
  #pragma unroll
  for (int mf = 0; mf < 4; ++mf) {
    #pragma unroll
    for (int q = 0; q < 4; ++q) {
      const int r_g = rowBase + wr*64 + mf*16 + fg*4 + q;
      const float ntr = norms[r_g];
      float vm = INF;
      #pragma unroll
      for (int nf = 0; nf < 4; ++nf) {
        const int c_g = colBase + wc*64 + nf*16 + fr;
        const float dot = acc[mf][nf][q];
        const float sq = ntr + ncol[nf] - 2.0f * dot;
        if (c_g == r_g + NB)   lpos1[r_g] = sq;   // unique writer
        if (c_g == r_g + 2*NB) lpos2[r_g] = sq;   // unique writer
        const bool excl = (c_g == r_g) || (c_g == r_g + NB) || (c_g == r_g + 2*NB);
        const float v = excl ? INF : fmaxf(sq, 0.0f);
        vm = fminf(vm, v);
      }
      #pragma unroll
      for (int off = 1; off < 16; off <<= 1)
        vm = fminf(vm, __shfl_xor(vm, off));
      if (fr == 0)
        atomicMin(minsq + r_g, __float_as_uint(vm));  // nonneg floats order as uints
    }
  }
}

__global__ __launch_bounds__(1024) void finalize(
    const float* __restrict__ lpos1, const float* __restrict__ lpos2,
    const float* __restrict__ dist12, const u32* __restrict__ minsq,
    float* __restrict__ out)
{
  __shared__ float red[16];
  const int tid = threadIdx.x;
  float s = 0.f;
  for (int r = tid; r < NB; r += 1024) {
    float l1 = sqrtf(fmaxf(lpos1[r], 0.f));
    float l2 = sqrtf(fmaxf(lpos2[r], 0.f));
    float neg = sqrtf(__uint_as_float(minsq[r]));   // already clamped >= 0
    float pos = l1 + l2 + dist12[r];
    s += fmaxf(pos - neg + 0.1f, 0.f) + fmaxf(l1, l2);
  }
  #pragma unroll
  for (int off = 32; off; off >>= 1) s += __shfl_down(s, off);
  if ((tid & 63) == 0) red[tid >> 6] = s;
  __syncthreads();
  if (tid == 0) {
    float t = 0.f;
    #pragma unroll
    for (int i = 0; i < 16; ++i) t += red[i];
    out[0] = t * (1.0f / NB);
  }
}

extern "C" void kernel_launch(void* const* d_in, const int* in_sizes, int n_in,
                              void* d_out, int out_size, void* d_ws, size_t ws_size,
                              hipStream_t stream) {
  const float* ts = (const float*)d_in[0];
  const float* i1 = (const float*)d_in[1];
  const float* i2 = (const float*)d_in[2];
  float* out = (float*)d_out;

  char* p = (char*)d_ws;
  u16* reps    = (u16*)p;            p += (size_t)NREPS * ND * sizeof(u16);  // 12.6 MB
  float* norms = (float*)p;          p += (size_t)NREPS * sizeof(float);
  float* dist12 = (float*)p;         p += (size_t)NB * sizeof(float);
  u32* minsq   = (u32*)p;            p += (size_t)NB * sizeof(u32);
  float* lpos1 = (float*)p;          p += (size_t)NB * sizeof(float);
  float* lpos2 = (float*)p;          p += (size_t)NB * sizeof(float);

  prep_all<<<NB, 256, 0, stream>>>(ts, i1, i2, reps, norms, dist12, minsq);
  gemm_min<<<(NB/BM) * (NREPS/BN), 256, 0, stream>>>(reps, norms, minsq, lpos1, lpos2);
  finalize<<<1, 1024, 0, stream>>>(lpos1, lpos2, dist12, minsq, out);
}

// Round 6
// 190.059 us; speedup vs baseline: 1.0625x; 1.0625x over previous
//
#include <hip/hip_runtime.h>
#include <hip/hip_bf16.h>

typedef unsigned short u16;
typedef unsigned int u32;
typedef __attribute__((ext_vector_type(8))) short bf16x8;
typedef __attribute__((ext_vector_type(4))) float f32x4;

#define NB 4096
#define ND 512
#define NREPS (3*NB)
#define BM 128
#define BN 128
#define BK 64
#define NKT (ND/BK)      // 8 K-tiles
#define TSZ (BM*BK)      // 8192 elems per tile buffer

// global -> LDS direct DMA, 16B/lane; LDS dest wave-uniform base + lane*16.
#define GLD16(gp, lp)                                                         \
  __builtin_amdgcn_global_load_lds(                                           \
      (const __attribute__((address_space(1))) void*)(gp),                    \
      (__attribute__((address_space(3))) void*)(lp), 16, 0, 0)

__device__ __forceinline__ u16 f2bf(float f) {
  union { float f; u32 u; } v; v.f = f;
  u32 u = v.u;
  u32 r = (u + 0x7FFFu + ((u >> 16) & 1u)) >> 16;  // round-to-nearest-even
  return (u16)r;
}

// Fused prep: waves 0..2 convert ts/i1/i2 row r -> bf16 reps + fp32 norms;
// i1/i2 rows pass through LDS to wave 3 (dist12 + minsq init).
__global__ __launch_bounds__(256) void prep_all(
    const float* __restrict__ ts, const float* __restrict__ i1,
    const float* __restrict__ i2, u16* __restrict__ reps,
    float* __restrict__ norms, float* __restrict__ dist12,
    u32* __restrict__ minsq)
{
  __shared__ float s1[ND], s2[ND];
  const int r = blockIdx.x;
  const int tid = threadIdx.x;
  const int wave = tid >> 6, lane = tid & 63;

  if (wave < 3) {
    const float* src = (wave == 0) ? ts + (size_t)r * ND
                     : (wave == 1) ? i1 + (size_t)r * ND
                     :               i2 + (size_t)r * ND;
    const float4* s4 = (const float4*)src;
    float4 a = s4[lane*2+0];
    float4 b = s4[lane*2+1];
    if (wave == 1) { ((float4*)s1)[lane*2+0] = a; ((float4*)s1)[lane*2+1] = b; }
    if (wave == 2) { ((float4*)s2)[lane*2+0] = a; ((float4*)s2)[lane*2+1] = b; }
    float ss = a.x*a.x + a.y*a.y + a.z*a.z + a.w*a.w
             + b.x*b.x + b.y*b.y + b.z*b.z + b.w*b.w;
    uint4 pk;
    pk.x = (u32)f2bf(a.x) | ((u32)f2bf(a.y) << 16);
    pk.y = (u32)f2bf(a.z) | ((u32)f2bf(a.w) << 16);
    pk.z = (u32)f2bf(b.x) | ((u32)f2bf(b.y) << 16);
    pk.w = (u32)f2bf(b.z) | ((u32)f2bf(b.w) << 16);
    *(uint4*)(reps + (size_t)(wave*NB + r) * ND + lane*8) = pk;
    #pragma unroll
    for (int off = 32; off; off >>= 1) ss += __shfl_down(ss, off);
    if (lane == 0) norms[wave*NB + r] = ss;
  }
  __syncthreads();
  if (wave == 3) {
    float ss = 0.f;
    #pragma unroll
    for (int i = 0; i < 2; ++i) {
      float4 a = ((float4*)s1)[lane*2+i];
      float4 b = ((float4*)s2)[lane*2+i];
      float d0 = a.x - b.x + 1e-6f, d1 = a.y - b.y + 1e-6f;
      float d2 = a.z - b.z + 1e-6f, d3 = a.w - b.w + 1e-6f;
      ss += d0*d0 + d1*d1 + d2*d2 + d3*d3;
    }
    #pragma unroll
    for (int off = 32; off; off >>= 1) ss += __shfl_down(ss, off);
    if (lane == 0) { dist12[r] = sqrtf(ss); minsq[r] = 0x7F800000u; }
  }
}

// Fused distance-GEMM + per-row min + diagonal picks.
// 128x128 tile, BK=64, 4 waves (2x2), 2-phase double-buffered LDS (64 KiB):
//   prologue: STAGE(buf0, k=0); sync
//   step t:   STAGE(buf[t^1], k(t+1))  [issue-early]
//             ds_read frags(buf[t]) ; 32 MFMA
//             __syncthreads()          [vmcnt(0)+lgkmcnt(0)+barrier, once/step]
//   last step peeled: compute only.
// Grid: dim3(32,96), M-fastest (R2 order) — concurrent blocks cover all of A
// (4 MB, fits aggregate L2) and share per-column B tiles. The R5 XCD swizzle
// quadrupled FETCH_SIZE (each XCD streamed all of B through its private L2).
// LDS linear; XOR swizzle applied on per-lane GLOBAL source granule (m173).
__global__ __launch_bounds__(256) void gemm_min(
    const u16* __restrict__ reps, const float* __restrict__ norms,
    u32* __restrict__ minsq, float* __restrict__ lpos1,
    float* __restrict__ lpos2)
{
  __shared__ u16 As[2*TSZ];
  __shared__ u16 Bs[2*TSZ];
  const int tid  = threadIdx.x;
  const int lane = tid & 63;
  const int wave = tid >> 6;
  const int wr = wave >> 1, wc = wave & 1;
  const int fr = lane & 15, fg = lane >> 4;

  const int rowBase = blockIdx.x * BM;   // ts rows
  const int colBase = blockIdx.y * BN;   // reps rows

  // Staging geometry: thread's 4 A-chunks + 4 B-chunks, 8 rows per chunk
  // (64 lanes x 16B = 1 KiB per GLD). Source granule is XOR-swizzled.
  const int rloc = lane >> 3;          // row within 8-row chunk
  const int sp   = lane & 7;           // physical 16B slot within row
  const u16* srcA[4]; const u16* srcB[4];
  u16* dstA[4]; u16* dstB[4];
  #pragma unroll
  for (int i = 0; i < 4; ++i) {
    const int r = wave*32 + i*8 + rloc;          // tile-local row 0..127
    const int g = sp ^ (r & 7);                  // swizzled source granule
    srcA[i] = reps + (size_t)(rowBase + r) * ND + g*8;
    srcB[i] = reps + (size_t)(colBase + r) * ND + g*8;
    dstA[i] = &As[(wave*32 + i*8) * BK];         // wave-uniform LDS base
    dstB[i] = &Bs[(wave*32 + i*8) * BK];
  }

#define STAGE(buf, koff)                                                      \
  { _Pragma("unroll")                                                         \
    for (int i = 0; i < 4; ++i) {                                             \
      GLD16(srcA[i] + (koff), dstA[i] + (buf)*TSZ);                           \
      GLD16(srcB[i] + (koff), dstB[i] + (buf)*TSZ);                           \
    } }

  f32x4 acc[4][4];
  const f32x4 zero = {0.f, 0.f, 0.f, 0.f};
  #pragma unroll
  for (int i = 0; i < 4; ++i)
    #pragma unroll
    for (int j = 0; j < 4; ++j)
      acc[i][j] = zero;

#define COMPUTE(cur)                                                          \
  { const u16* Sa = As + (cur)*TSZ;                                           \
    const u16* Sb = Bs + (cur)*TSZ;                                           \
    bf16x8 af[4][2], bfr[4][2];                                               \
    _Pragma("unroll")                                                         \
    for (int mf = 0; mf < 4; ++mf)                                            \
      _Pragma("unroll")                                                       \
      for (int ks = 0; ks < 2; ++ks) {                                        \
        const int rowA = wr*64 + mf*16 + fr;                                  \
        const int slot = ks*4 + fg;                                           \
        af[mf][ks]  = *(const bf16x8*)&Sa[rowA*BK + (slot ^ (rowA & 7))*8];   \
        const int rowB = wc*64 + mf*16 + fr;                                  \
        bfr[mf][ks] = *(const bf16x8*)&Sb[rowB*BK + (slot ^ (rowB & 7))*8];   \
      }                                                                       \
    _Pragma("unroll")                                                         \
    for (int ks = 0; ks < 2; ++ks)                                            \
      _Pragma("unroll")                                                       \
      for (int mf = 0; mf < 4; ++mf)                                          \
        _Pragma("unroll")                                                     \
        for (int nf = 0; nf < 4; ++nf)                                        \
          acc[mf][nf] = __builtin_amdgcn_mfma_f32_16x16x32_bf16(              \
              af[mf][ks], bfr[nf][ks], acc[mf][nf], 0, 0, 0);                 \
  }

  // Prologue: tile 0 into buffer 0, full drain once.
  STAGE(0, 0);
  __syncthreads();
  // Steady state: issue next tile's loads, then compute current.
  #pragma unroll
  for (int t = 0; t < NKT-1; ++t) {
    STAGE((t & 1) ^ 1, (t+1)*BK);
    COMPUTE(t & 1);
    __syncthreads();   // vmcnt(0): next tile landed; all reads of cur done
  }
  COMPUTE((NKT-1) & 1);  // peeled: no stage, no trailing barrier needed

  // Epilogue: sq = nt + nc - 2*dot; diagonal picks; row-min with exclusions.
  // C layout: col = fr, row = fg*4 + q within each 16x16 fragment.
  float ncol[4];
  #pragma unroll
  for (int nf = 0; nf < 4; ++nf)
    ncol[nf] = norms[colBase + wc*64 + nf*16 + fr];
  const float INF = __builtin_inff();
  #pragma unroll
  for (int mf = 0; mf < 4; ++mf) {
    #pragma unroll
    for (int q = 0; q < 4; ++q) {
      const int r_g = rowBase + wr*64 + mf*16 + fg*4 + q;
      const float ntr = norms[r_g];
      float vm = INF;
      #pragma unroll
      for (int nf = 0; nf < 4; ++nf) {
        const int c_g = colBase + wc*64 + nf*16 + fr;
        const float dot = acc[mf][nf][q];
        const float sq = ntr + ncol[nf] - 2.0f * dot;
        if (c_g == r_g + NB)   lpos1[r_g] = sq;   // unique writer
        if (c_g == r_g + 2*NB) lpos2[r_g] = sq;   // unique writer
        const bool excl = (c_g == r_g) || (c_g == r_g + NB) || (c_g == r_g + 2*NB);
        const float v = excl ? INF : fmaxf(sq, 0.0f);
        vm = fminf(vm, v);
      }
      #pragma unroll
      for (int off = 1; off < 16; off <<= 1)
        vm = fminf(vm, __shfl_xor(vm, off));
      if (fr == 0)
        atomicMin(minsq + r_g, __float_as_uint(vm));  // nonneg floats order as uints
    }
  }
}

__global__ __launch_bounds__(1024) void finalize(
    const float* __restrict__ lpos1, const float* __restrict__ lpos2,
    const float* __restrict__ dist12, const u32* __restrict__ minsq,
    float* __restrict__ out)
{
  __shared__ float red[16];
  const int tid = threadIdx.x;
  float s = 0.f;
  for (int r = tid; r < NB; r += 1024) {
    float l1 = sqrtf(fmaxf(lpos1[r], 0.f));
    float l2 = sqrtf(fmaxf(lpos2[r], 0.f));
    float neg = sqrtf(__uint_as_float(minsq[r]));   // already clamped >= 0
    float pos = l1 + l2 + dist12[r];
    s += fmaxf(pos - neg + 0.1f, 0.f) + fmaxf(l1, l2);
  }
  #pragma unroll
  for (int off = 32; off; off >>= 1) s += __shfl_down(s, off);
  if ((tid & 63) == 0) red[tid >> 6] = s;
  __syncthreads();
  if (tid == 0) {
    float t = 0.f;
    #pragma unroll
    for (int i = 0; i < 16; ++i) t += red[i];
    out[0] = t * (1.0f / NB);
  }
}

extern "C" void kernel_launch(void* const* d_in, const int* in_sizes, int n_in,
                              void* d_out, int out_size, void* d_ws, size_t ws_size,
                              hipStream_t stream) {
  const float* ts = (const float*)d_in[0];
  const float* i1 = (const float*)d_in[1];
  const float* i2 = (const float*)d_in[2];
  float* out = (float*)d_out;

  char* p = (char*)d_ws;
  u16* reps    = (u16*)p;            p += (size_t)NREPS * ND * sizeof(u16);  // 12.6 MB
  float* norms = (float*)p;          p += (size_t)NREPS * sizeof(float);
  float* dist12 = (float*)p;         p += (size_t)NB * sizeof(float);
  u32* minsq   = (u32*)p;            p += (size_t)NB * sizeof(u32);
  float* lpos1 = (float*)p;          p += (size_t)NB * sizeof(float);
  float* lpos2 = (float*)p;          p += (size_t)NB * sizeof(float);

  prep_all<<<NB, 256, 0, stream>>>(ts, i1, i2, reps, norms, dist12, minsq);
  dim3 grid(NB / BM, NREPS / BN);   // 32 x 96, M-fastest (R2 locality)
  gemm_min<<<grid, 256, 0, stream>>>(reps, norms, minsq, lpos1, lpos2);
  finalize<<<1, 1024, 0, stream>>>(lpos1, lpos2, dist12, minsq, out);
}

// Round 7
// 144.155 us; speedup vs baseline: 1.4008x; 1.3184x over previous
//
#include <hip/hip_runtime.h>
#include <hip/hip_bf16.h>

typedef unsigned short u16;
typedef unsigned int u32;
typedef __attribute__((ext_vector_type(8))) short bf16x8;
typedef __attribute__((ext_vector_type(4))) float f32x4;

#define NB 4096
#define ND 512
#define NREPS (3*NB)
#define BM 128
#define BN 256
#define BK 64
#define NKT (ND/BK)      // 8 K-tiles
#define ASZ (BM*BK)      // 8192 elems (16 KiB)
#define BSZ (BN*BK)      // 16384 elems (32 KiB)

// global -> LDS direct DMA, 16B/lane; LDS dest wave-uniform base + lane*16.
#define GLD16(gp, lp)                                                         \
  __builtin_amdgcn_global_load_lds(                                           \
      (const __attribute__((address_space(1))) void*)(gp),                    \
      (__attribute__((address_space(3))) void*)(lp), 16, 0, 0)

__device__ __forceinline__ u16 f2bf(float f) {
  union { float f; u32 u; } v; v.f = f;
  u32 u = v.u;
  u32 r = (u + 0x7FFFu + ((u >> 16) & 1u)) >> 16;  // round-to-nearest-even
  return (u16)r;
}

// Fused prep: waves 0..2 convert ts/i1/i2 row r -> bf16 reps + fp32 norms;
// i1/i2 rows pass through LDS to wave 3 (dist12 + minsq init).
__global__ __launch_bounds__(256) void prep_all(
    const float* __restrict__ ts, const float* __restrict__ i1,
    const float* __restrict__ i2, u16* __restrict__ reps,
    float* __restrict__ norms, float* __restrict__ dist12,
    u32* __restrict__ minsq)
{
  __shared__ float s1[ND], s2[ND];
  const int r = blockIdx.x;
  const int tid = threadIdx.x;
  const int wave = tid >> 6, lane = tid & 63;

  if (wave < 3) {
    const float* src = (wave == 0) ? ts + (size_t)r * ND
                     : (wave == 1) ? i1 + (size_t)r * ND
                     :               i2 + (size_t)r * ND;
    const float4* s4 = (const float4*)src;
    float4 a = s4[lane*2+0];
    float4 b = s4[lane*2+1];
    if (wave == 1) { ((float4*)s1)[lane*2+0] = a; ((float4*)s1)[lane*2+1] = b; }
    if (wave == 2) { ((float4*)s2)[lane*2+0] = a; ((float4*)s2)[lane*2+1] = b; }
    float ss = a.x*a.x + a.y*a.y + a.z*a.z + a.w*a.w
             + b.x*b.x + b.y*b.y + b.z*b.z + b.w*b.w;
    uint4 pk;
    pk.x = (u32)f2bf(a.x) | ((u32)f2bf(a.y) << 16);
    pk.y = (u32)f2bf(a.z) | ((u32)f2bf(a.w) << 16);
    pk.z = (u32)f2bf(b.x) | ((u32)f2bf(b.y) << 16);
    pk.w = (u32)f2bf(b.z) | ((u32)f2bf(b.w) << 16);
    *(uint4*)(reps + (size_t)(wave*NB + r) * ND + lane*8) = pk;
    #pragma unroll
    for (int off = 32; off; off >>= 1) ss += __shfl_down(ss, off);
    if (lane == 0) norms[wave*NB + r] = ss;
  }
  __syncthreads();
  if (wave == 3) {
    float ss = 0.f;
    #pragma unroll
    for (int i = 0; i < 2; ++i) {
      float4 a = ((float4*)s1)[lane*2+i];
      float4 b = ((float4*)s2)[lane*2+i];
      float d0 = a.x - b.x + 1e-6f, d1 = a.y - b.y + 1e-6f;
      float d2 = a.z - b.z + 1e-6f, d3 = a.w - b.w + 1e-6f;
      ss += d0*d0 + d1*d1 + d2*d2 + d3*d3;
    }
    #pragma unroll
    for (int off = 32; off; off >>= 1) ss += __shfl_down(ss, off);
    if (lane == 0) { dist12[r] = sqrtf(ss); minsq[r] = 0x7F800000u; }
  }
}

// Fused distance-GEMM + per-row min + diagonal picks.
// 128x256 tile, BK=64, 8 waves (2M x 4N), wave-tile 64x64, single-buffer
// 48 KiB LDS, proven R2 schedule: stage -> sync -> compute -> sync.
// Rationale: total L2->LDS staged bytes = M*N*K*2*(1/BM+1/BN); BN=256 cuts
// it 805->604 MB (-25%) vs 128^2 while keeping ~2-3 blocks/CU resident
// (the R6 double-buffer lost occupancy and regressed).
// Grid dim3(32,48), M-fastest: concurrent blocks cover all of A (L2-resident),
// share per-column B tiles (R5's XCD swizzle quadrupled FETCH -> reverted).
// LDS linear; XOR swizzle applied on per-lane GLOBAL source granule (m173).
__global__ __launch_bounds__(512) void gemm_min(
    const u16* __restrict__ reps, const float* __restrict__ norms,
    u32* __restrict__ minsq, float* __restrict__ lpos1,
    float* __restrict__ lpos2)
{
  __shared__ u16 As[ASZ];
  __shared__ u16 Bs[BSZ];
  const int tid  = threadIdx.x;
  const int lane = tid & 63;
  const int wave = tid >> 6;          // 0..7
  const int wr = wave >> 2;           // 0..1 (M half)
  const int wc = wave & 3;            // 0..3 (N quarter)
  const int fr = lane & 15, fg = lane >> 4;

  const int rowBase = blockIdx.x * BM;   // ts rows
  const int colBase = blockIdx.y * BN;   // reps rows

  // Staging: A = 16 chunks of 8 rows (2/wave), B = 32 chunks (4/wave);
  // each GLD16 covers 8 rows (64 lanes x 16B = 1 KiB). Src granule swizzled.
  const int rloc = lane >> 3;          // row within 8-row chunk
  const int sp   = lane & 7;           // physical 16B slot within row
  const u16* srcA[2]; u16* dstA[2];
  const u16* srcB[4]; u16* dstB[4];
  #pragma unroll
  for (int i = 0; i < 2; ++i) {
    const int r = wave*16 + i*8 + rloc;          // tile-local A row 0..127
    const int g = sp ^ (r & 7);
    srcA[i] = reps + (size_t)(rowBase + r) * ND + g*8;
    dstA[i] = &As[(wave*16 + i*8) * BK];         // wave-uniform LDS base
  }
  #pragma unroll
  for (int i = 0; i < 4; ++i) {
    const int r = wave*32 + i*8 + rloc;          // tile-local B row 0..255
    const int g = sp ^ (r & 7);
    srcB[i] = reps + (size_t)(colBase + r) * ND + g*8;
    dstB[i] = &Bs[(wave*32 + i*8) * BK];
  }

  f32x4 acc[4][4];
  const f32x4 zero = {0.f, 0.f, 0.f, 0.f};
  #pragma unroll
  for (int i = 0; i < 4; ++i)
    #pragma unroll
    for (int j = 0; j < 4; ++j)
      acc[i][j] = zero;

  for (int kt = 0; kt < NKT; ++kt) {
    const int koff = kt * BK;
    #pragma unroll
    for (int i = 0; i < 2; ++i) GLD16(srcA[i] + koff, dstA[i]);
    #pragma unroll
    for (int i = 0; i < 4; ++i) GLD16(srcB[i] + koff, dstB[i]);
    __syncthreads();   // vmcnt(0) drain + barrier

    bf16x8 af[4][2], bfr[4][2];
    #pragma unroll
    for (int mf = 0; mf < 4; ++mf)
      #pragma unroll
      for (int ks = 0; ks < 2; ++ks) {
        const int rowA = wr*64 + mf*16 + fr;
        const int slot = ks*4 + fg;
        af[mf][ks]  = *(const bf16x8*)&As[rowA*BK + (slot ^ (rowA & 7))*8];
        const int rowB = wc*64 + mf*16 + fr;
        bfr[mf][ks] = *(const bf16x8*)&Bs[rowB*BK + (slot ^ (rowB & 7))*8];
      }
    #pragma unroll
    for (int ks = 0; ks < 2; ++ks)
      #pragma unroll
      for (int mf = 0; mf < 4; ++mf)
        #pragma unroll
        for (int nf = 0; nf < 4; ++nf)
          acc[mf][nf] = __builtin_amdgcn_mfma_f32_16x16x32_bf16(
              af[mf][ks], bfr[nf][ks], acc[mf][nf], 0, 0, 0);
    __syncthreads();
  }

  // Epilogue: sq = nt + nc - 2*dot; diagonal picks; row-min with exclusions.
  // C layout: col = fr, row = fg*4 + q within each 16x16 fragment.
  float ncol[4];
  #pragma unroll
  for (int nf = 0; nf < 4; ++nf)
    ncol[nf] = norms[colBase + wc*64 + nf*16 + fr];
  const float INF = __builtin_inff();
  #pragma unroll
  for (int mf = 0; mf < 4; ++mf) {
    #pragma unroll
    for (int q = 0; q < 4; ++q) {
      const int r_g = rowBase + wr*64 + mf*16 + fg*4 + q;
      const float ntr = norms[r_g];
      float vm = INF;
      #pragma unroll
      for (int nf = 0; nf < 4; ++nf) {
        const int c_g = colBase + wc*64 + nf*16 + fr;
        const float dot = acc[mf][nf][q];
        const float sq = ntr + ncol[nf] - 2.0f * dot;
        if (c_g == r_g + NB)   lpos1[r_g] = sq;   // unique writer
        if (c_g == r_g + 2*NB) lpos2[r_g] = sq;   // unique writer
        const bool excl = (c_g == r_g) || (c_g == r_g + NB) || (c_g == r_g + 2*NB);
        const float v = excl ? INF : fmaxf(sq, 0.0f);
        vm = fminf(vm, v);
      }
      #pragma unroll
      for (int off = 1; off < 16; off <<= 1)
        vm = fminf(vm, __shfl_xor(vm, off));
      if (fr == 0)
        atomicMin(minsq + r_g, __float_as_uint(vm));  // nonneg floats order as uints
    }
  }
}

__global__ __launch_bounds__(1024) void finalize(
    const float* __restrict__ lpos1, const float* __restrict__ lpos2,
    const float* __restrict__ dist12, const u32* __restrict__ minsq,
    float* __restrict__ out)
{
  __shared__ float red[16];
  const int tid = threadIdx.x;
  float s = 0.f;
  for (int r = tid; r < NB; r += 1024) {
    float l1 = sqrtf(fmaxf(lpos1[r], 0.f));
    float l2 = sqrtf(fmaxf(lpos2[r], 0.f));
    float neg = sqrtf(__uint_as_float(minsq[r]));   // already clamped >= 0
    float pos = l1 + l2 + dist12[r];
    s += fmaxf(pos - neg + 0.1f, 0.f) + fmaxf(l1, l2);
  }
  #pragma unroll
  for (int off = 32; off; off >>= 1) s += __shfl_down(s, off);
  if ((tid & 63) == 0) red[tid >> 6] = s;
  __syncthreads();
  if (tid == 0) {
    float t = 0.f;
    #pragma unroll
    for (int i = 0; i < 16; ++i) t += red[i];
    out[0] = t * (1.0f / NB);
  }
}

extern "C" void kernel_launch(void* const* d_in, const int* in_sizes, int n_in,
                              void* d_out, int out_size, void* d_ws, size_t ws_size,
                              hipStream_t stream) {
  const float* ts = (const float*)d_in[0];
  const float* i1 = (const float*)d_in[1];
  const float* i2 = (const float*)d_in[2];
  float* out = (float*)d_out;

  char* p = (char*)d_ws;
  u16* reps    = (u16*)p;            p += (size_t)NREPS * ND * sizeof(u16);  // 12.6 MB
  float* norms = (float*)p;          p += (size_t)NREPS * sizeof(float);
  float* dist12 = (float*)p;         p += (size_t)NB * sizeof(float);
  u32* minsq   = (u32*)p;            p += (size_t)NB * sizeof(u32);
  float* lpos1 = (float*)p;          p += (size_t)NB * sizeof(float);
  float* lpos2 = (float*)p;          p += (size_t)NB * sizeof(float);

  prep_all<<<NB, 256, 0, stream>>>(ts, i1, i2, reps, norms, dist12, minsq);
  dim3 grid(NB / BM, NREPS / BN);   // 32 x 48, M-fastest (L2 locality)
  gemm_min<<<grid, 512, 0, stream>>>(reps, norms, minsq, lpos1, lpos2);
  finalize<<<1, 1024, 0, stream>>>(lpos1, lpos2, dist12, minsq, out);
}